// Round 8
// baseline (1534.008 us; speedup 1.0000x reference)
//
#include <hip/hip_runtime.h>
#include <hip/hip_bf16.h>

// B=256, S=512, D=128, R=2048, H=0.5
#define Bn 256
#define Sn 512
#define Dn 128
#define Rn 2048
#define TBv 32            // time-block
#define NBLK (Sn / TBv)   // 16 time-blocks
#define Gn 4              // r-slices
#define RG (Rn / Gn)      // 512 r per workgroup slice
#define LDX 132           // Xs row stride (bf16)
#define LDPs 516          // PX row stride (bf16): 512 + 4 pad

using bf16_t = __hip_bfloat16;
typedef short bf16x8 __attribute__((ext_vector_type(8)));
typedef float f32x4 __attribute__((ext_vector_type(4)));

__device__ __forceinline__ float clip5(float v) { return fminf(fmaxf(v, -5.f), 5.f); }

// K0: preds := bias broadcast; weights fp32->bf16; zero losses.
__global__ __launch_bounds__(256) void k_init(const float* __restrict__ Wp,
                                              const float* __restrict__ Wr,
                                              const float* __restrict__ br,
                                              bf16_t* __restrict__ Wp_b,
                                              bf16_t* __restrict__ Wr_b,
                                              float* __restrict__ preds,
                                              float* __restrict__ losses) {
  const int i = blockIdx.x * 256 + threadIdx.x;  // f32x4 index over Bn*Sn*Dn/4
  const f32x4 bv = *(const f32x4*)(br + (i & 31) * 4);
  *((f32x4*)preds + i) = bv;
  if (i < Rn * Dn) {
    Wp_b[i] = __float2bfloat16(Wp[i]);
    Wr_b[i] = __float2bfloat16(Wr[i]);
  }
  if (i == 0) { losses[0] = 0.f; losses[1] = 0.f; }
}

// K1: input oscillator scan per (b,d) -> Xin bf16 [b][t][d]; pc_loss_in.
__global__ __launch_bounds__(128) void k_inosc(const float* __restrict__ inp,
                                               const float* __restrict__ om,
                                               const float* __restrict__ ga,
                                               const float* __restrict__ al,
                                               bf16_t* __restrict__ Xin,
                                               float* __restrict__ loss_in) {
  const int d = threadIdx.x, b = blockIdx.x;
  const float w2 = om[d] * om[d];
  const float g2 = 2.f * fabsf(ga[d]);
  const float a = al[d];
  const float* ip = inp + (size_t)b * Sn * Dn + d;
  bf16_t* xp = Xin + (size_t)b * Sn * Dn + d;
  float x = 0.f, y = 0.f, pc = 0.f;
  float fv[16];
#pragma unroll
  for (int j = 0; j < 16; ++j) fv[j] = __builtin_nontemporal_load(ip + (size_t)j * Dn);
  for (int tb = 0; tb < 32; ++tb) {
    float fn[16];
    if (tb < 31) {
#pragma unroll
      for (int j = 0; j < 16; ++j)
        fn[j] = __builtin_nontemporal_load(ip + (size_t)((tb + 1) * 16 + j) * Dn);
    }
#pragma unroll
    for (int j = 0; j < 16; ++j) {
      const int t = tb * 16 + j;
      const float f = fv[j];
      if (t > 0) { const float e = x - f; pc += e * e; }
      const float accel = a * f - g2 * y - w2 * x;
      const float xn = clip5(x + 0.5f * y);
      const float yn = clip5(y + 0.5f * accel);
      xp[(size_t)t * Dn] = __float2bfloat16(xn);
      x = xn; y = yn;
    }
#pragma unroll
    for (int j = 0; j < 16; ++j) fv[j] = fn[j];
  }
#pragma unroll
  for (int o = 32; o > 0; o >>= 1) pc += __shfl_down(pc, o, 64);
  if ((threadIdx.x & 63) == 0)
    atomicAdd(loss_in, pc * (1.f / ((float)Bn * (float)Dn)));
}

// K2: fused proj GEMM + reservoir/output scan + readout GEMM.
// Grid Bn*Gn, swizzled: b = idx&255, g = idx>>8 (same-b slices -> same XCD).
// 512 thr (8 waves), ~43KB LDS -> 3 WGs/CU.
__global__ __launch_bounds__(512, 6) void k_fused(
    const bf16_t* __restrict__ Xin,
    const bf16_t* __restrict__ Wp, const float* __restrict__ bp,
    const float* __restrict__ omr, const float* __restrict__ gar,
    const float* __restrict__ alr,
    const float* __restrict__ omo, const float* __restrict__ gao,
    const float* __restrict__ alo,
    const bf16_t* __restrict__ Wr,
    float* __restrict__ preds, float* __restrict__ loss_out) {
  __shared__ bf16_t Xs[TBv * LDX];    // 8.25 KB
  __shared__ bf16_t PX[TBv * LDPs];   // 32.25 KB (proj slice, x_out in place)
  __shared__ float bpS[RG];           // 2 KB
  __shared__ float smo[8];

  const int tid = threadIdx.x;
  const int b = blockIdx.x & 255, g = blockIdx.x >> 8;
  const int rbase = g * RG;
  const int wv = tid >> 6, lane = tid & 63;
  const int lr = lane & 15, lq = lane >> 4;

  bpS[tid] = bp[rbase + tid];

  // reservoir/output oscillator state: each thread owns one r = rbase + tid
  float xr = 0.f, yr = 0.f, xo = 0.f, yo = 0.f, pc = 0.f;
  const int rg = rbase + tid;
  const float w2r = omr[rg] * omr[rg];
  const float g2r = 2.f * fabsf(gar[rg]);
  const float ar = alr[rg];
  const float w2o = omo[rg] * omo[rg];
  const float g2o = 2.f * fabsf(gao[rg]);
  const float ao = alo[rg];

  const bf16_t* xinb = Xin + (size_t)b * Sn * Dn;

  // prologue: stage first Xin tile (32 x 128 bf16 = 512 x 16B chunks, 1/thread)
  *(uint4*)&Xs[(tid >> 4) * LDX + (tid & 15) * 8] =
      *(const uint4*)(xinb + (size_t)(tid >> 4) * Dn + (tid & 15) * 8);
  __syncthreads();

  for (int blk = 0; blk < NBLK; ++blk) {
    const int t0 = blk * TBv;

    // ---- Phase B: proj slice [32 x 512] = Xs[32x128] @ Wp_slice^T + bias -> PX ----
    {
      const int cb = wv * 64;  // wave's 64 local cols = 4 tiles of 16
#pragma unroll
      for (int ct = 0; ct < 4; ++ct) {
        const int cl = cb + ct * 16;
        const bf16_t* wpb = Wp + (size_t)(rbase + cl + lr) * Dn + lq * 8;
        bf16x8 bfr[4];
#pragma unroll
        for (int k = 0; k < 4; ++k) bfr[k] = *(const bf16x8*)(wpb + k * 32);
        const float bv = bpS[cl + lr];
#pragma unroll
        for (int rt = 0; rt < 2; ++rt) {
          f32x4 a = (f32x4)0.f;
#pragma unroll
          for (int k = 0; k < 4; ++k) {
            bf16x8 af = *(const bf16x8*)&Xs[(rt * 16 + lr) * LDX + k * 32 + lq * 8];
            a = __builtin_amdgcn_mfma_f32_16x16x32_bf16(af, bfr[k], a, 0, 0, 0);
          }
#pragma unroll
          for (int r = 0; r < 4; ++r)
            PX[(rt * 16 + lq * 4 + r) * LDPs + cl + lr] = __float2bfloat16(a[r] + bv);
        }
      }
    }

    // issue next Xin tile load (latency spans C+D; Xs reads are done after B)
    uint4 sv;
    if (blk + 1 < NBLK) {
      const bf16_t* src = xinb + (size_t)(t0 + TBv) * Dn;
      sv = *(const uint4*)(src + (size_t)(tid >> 4) * Dn + (tid & 15) * 8);
    }
    __syncthreads();  // PX complete

    // ---- Phase C: reservoir + output oscillators, in place (all 512 threads) ----
    {
      float pv = __bfloat162float(PX[0 * LDPs + tid]);
      for (int tt = 0; tt < TBv; ++tt) {
        float pn = pv;
        if (tt + 1 < TBv) pn = __bfloat162float(PX[(tt + 1) * LDPs + tid]);
        const float acr = ar * pv - g2r * yr - w2r * xr;
        const float xrn = clip5(xr + 0.5f * yr);
        const float yrn = clip5(yr + 0.5f * acr);
        const float aco = ao * xrn - g2o * yo - w2o * xo;
        const float xon = clip5(xo + 0.5f * yo);
        const float yon = clip5(yo + 0.5f * aco);
        const float e = xon - xrn;
        pc += e * e;
        xr = xrn; yr = yrn; xo = xon; yo = yon;
        PX[tt * LDPs + tid] = __float2bfloat16(xon);
        pv = pn;
      }
    }
    __syncthreads();

    // ---- Phase D: preds[32 x 128] += PX[32x512] @ Wr[:, slice]^T (atomic fan-in 4) ----
    {
      const int d0 = wv * 16;
      const bf16_t* wrb = Wr + (size_t)(d0 + lr) * Rn + rbase + lq * 8;
      f32x4 acc[2] = {(f32x4)0.f, (f32x4)0.f};
      bf16x8 bcur = *(const bf16x8*)(wrb);
#pragma unroll
      for (int k0 = 0; k0 < RG; k0 += 32) {
        bf16x8 bnxt = bcur;
        if (k0 + 32 < RG) bnxt = *(const bf16x8*)(wrb + k0 + 32);
        bf16x8 a0 = *(const bf16x8*)&PX[(0 + lr) * LDPs + k0 + lq * 8];
        bf16x8 a1 = *(const bf16x8*)&PX[(16 + lr) * LDPs + k0 + lq * 8];
        acc[0] = __builtin_amdgcn_mfma_f32_16x16x32_bf16(a0, bcur, acc[0], 0, 0, 0);
        acc[1] = __builtin_amdgcn_mfma_f32_16x16x32_bf16(a1, bcur, acc[1], 0, 0, 0);
        bcur = bnxt;
      }
      // commit staged Xs while atomics drain
      if (blk + 1 < NBLK)
        *(uint4*)&Xs[(tid >> 4) * LDX + (tid & 15) * 8] = sv;
      float* outb = preds + (size_t)b * Sn * Dn + (size_t)t0 * Dn;
      const int col = d0 + lr;
#pragma unroll
      for (int i = 0; i < 2; ++i)
#pragma unroll
        for (int r = 0; r < 4; ++r)
          atomicAdd(outb + (size_t)(i * 16 + lq * 4 + r) * Dn + col, acc[i][r]);
    }
    __syncthreads();  // Xs staged AND PX reads drained
  }

  // ---- pc_loss_out reduction: one atomicAdd per WG ----
#pragma unroll
  for (int o = 32; o > 0; o >>= 1) pc += __shfl_down(pc, o, 64);
  if (lane == 0) smo[wv] = pc;
  __syncthreads();
  if (tid == 0) {
    float so = 0.f;
#pragma unroll
    for (int w = 0; w < 8; ++w) so += smo[w];
    atomicAdd(loss_out, so * (1.f / ((float)Bn * (float)Rn)));
  }
}

extern "C" void kernel_launch(void* const* d_in, const int* in_sizes, int n_in,
                              void* d_out, int out_size, void* d_ws, size_t ws_size,
                              hipStream_t stream) {
  const float* inputs    = (const float*)d_in[0];
  const float* omega_in  = (const float*)d_in[1];
  const float* gamma_in  = (const float*)d_in[2];
  const float* alpha_in  = (const float*)d_in[3];
  const float* W_proj    = (const float*)d_in[4];
  const float* b_proj    = (const float*)d_in[5];
  const float* omega_res = (const float*)d_in[6];
  const float* gamma_res = (const float*)d_in[7];
  const float* alpha_res = (const float*)d_in[8];
  const float* omega_out = (const float*)d_in[9];
  const float* gamma_out = (const float*)d_in[10];
  const float* alpha_out = (const float*)d_in[11];
  const float* W_read    = (const float*)d_in[12];
  const float* b_read    = (const float*)d_in[13];

  float* out = (float*)d_out;
  float* losses = out + (size_t)Bn * Sn * Dn;  // preds | pc_loss_in | pc_loss_out

  // ws: Wp_b 512KB | Wr_b 512KB | Xin bf16 32MB  (~33MB total)
  bf16_t* Wp_b = (bf16_t*)d_ws;
  bf16_t* Wr_b = Wp_b + (size_t)Rn * Dn;
  bf16_t* Xin  = Wr_b + (size_t)Rn * Dn;

  k_init<<<(Bn * Sn * Dn / 4) / 256, 256, 0, stream>>>(W_proj, W_read, b_read,
                                                       Wp_b, Wr_b, out, losses);
  k_inosc<<<Bn, 128, 0, stream>>>(inputs, omega_in, gamma_in, alpha_in, Xin, losses);
  k_fused<<<Bn * Gn, 512, 0, stream>>>(Xin, Wp_b, b_proj,
                                       omega_res, gamma_res, alpha_res,
                                       omega_out, gamma_out, alpha_out,
                                       Wr_b, out, losses + 1);
}